// Round 11
// baseline (273.851 us; speedup 1.0000x reference)
//
#include <hip/hip_runtime.h>
#include <math.h>

#define BATCH 16
#define SEQLEN 4096
#define INPUT_DIM 57
#define D_MODEL 256
#define D_INNER 512
#define D_STATE 8
#define HEADDIM 16
#define NHEADS 32
#define CHUNK 8
#define NC (SEQLEN/CHUNK)          // 512
#define NCH (NC/2)                 // 256 superchunks (2 chunks composed)
#define CONV_DIM 528
#define D_INPROJ 1072
#define OUT_SIZE 6
#define NTOK (BATCH*SEQLEN)        // 65536
#define NSEG 16                    // segments per (b,h)
#define SEGC (NCH/NSEG)            // 16 superchunks per segment

__device__ __forceinline__ unsigned short f2bf(float f) {   // RNE bf16, finite
    unsigned v = __float_as_uint(f);
    return (unsigned short)((v + 0x7fffu + ((v >> 16) & 1u)) >> 16);
}
// HW packed RNE f32->bf16 pair: dst.lo = bf(lo), dst.hi = bf(hi). 1 VALU inst.
__device__ __forceinline__ unsigned pack_bf2(float lo, float hi) {
    unsigned r;
    asm("v_cvt_pk_bf16_f32 %0, %1, %2" : "=v"(r) : "v"(lo), "v"(hi));
    return r;
}
__device__ __forceinline__ float fsilu(float v) {
    return v * __builtin_amdgcn_rcpf(1.f + __expf(-v));
}

typedef __attribute__((ext_vector_type(8))) short bf16x8;
typedef __attribute__((ext_vector_type(4))) float f32x4;

// ---------------------------------------------------------------------------
// P0 v3: fold W_in into W_inproj etc.; also zeroes pred (fused atomically
// accumulates into it now).
// ---------------------------------------------------------------------------
__global__ __launch_bounds__(256) void precompute_kernel(
    const float* __restrict__ W_in,
    const float* __restrict__ b_in,
    const float* __restrict__ W_inproj,
    const float* __restrict__ W_out,
    const float* __restrict__ W_cls,
    float* __restrict__ WcT,    // [57][1072]
    float* __restrict__ b_comb, // [1072]
    unsigned short* __restrict__ Wbf, // [1024][64]
    float* __restrict__ W_oc,   // [6][512]
    float* __restrict__ pred)   // [B][32][512] zero-fill
{
    __shared__ double red[256];
    const int blk = blockIdx.x;
    const int tid = threadIdx.x;
    if (blk < D_INPROJ) {
        const int n = blk;
        const int t = tid & 63, ms = tid >> 6;      // ms = 0..3
        double a0 = 0.0, a1 = 0.0;
        const int m0 = ms*64;
        if (t < INPUT_DIM) {
            for (int m = m0; m < m0 + 64; m += 2) {
                a0 += (double)W_inproj[n*D_MODEL+m  ] * (double)W_in[(m  )*INPUT_DIM+t];
                a1 += (double)W_inproj[n*D_MODEL+m+1] * (double)W_in[(m+1)*INPUT_DIM+t];
            }
        } else if (t == INPUT_DIM) {
            for (int m = m0; m < m0 + 64; m += 2) {
                a0 += (double)W_inproj[n*D_MODEL+m  ] * (double)b_in[m  ];
                a1 += (double)W_inproj[n*D_MODEL+m+1] * (double)b_in[m+1];
            }
        }
        red[tid] = a0 + a1;
        __syncthreads();
        if (tid < 64) {
            double acc = (red[tid] + red[tid+64]) + (red[tid+128] + red[tid+192]);
            if (t < INPUT_DIM) {
                WcT[t*D_INPROJ + n] = (float)acc;
                if (n < 1024) Wbf[n*64 + t] = f2bf((float)acc);
            } else {
                if (t == INPUT_DIM) b_comb[n] = (float)acc;
                if (n < 1024) Wbf[n*64 + t] = 0;   // k pad 57..63
            }
        }
    } else {
        const int d = blk - D_INPROJ;               // 0..511
        // zero pred (262144 floats / 512 blocks / 256 threads = 2 each)
        const int zi = d*256 + tid;
        pred[zi] = 0.f;
        pred[zi + 131072] = 0.f;
        const int o = tid >> 5;          // 0..7 (6 active)
        const int lp = tid & 31;
        double a = 0.0;
        if (o < OUT_SIZE) {
            const int m0 = lp*8;
            #pragma unroll
            for (int mm = 0; mm < 8; ++mm) {
                int m = m0 + mm;
                a += (double)W_cls[o*D_MODEL+m] * (double)W_out[m*D_INNER+d];
            }
        }
        #pragma unroll
        for (int off = 16; off > 0; off >>= 1)
            a += __shfl_down(a, off, 32);
        if (o < OUT_SIZE && lp == 0)
            W_oc[o*D_INNER + d] = (float)a;
    }
}

// ---------------------------------------------------------------------------
// FUSED v3.1 (best known: ~182 us, VGPR 44): register-disciplined n-split.
// Each quad computes states n = joff..joff+3 over ALL 8 rows of its chunk;
// partner-row products via transient fp32 xor16 shfl inside the r-loop.
// quad0 writes SGg words 0-3, quad1 words 4-7.
//
// LDS arena 'uni' (float word offsets), regions by liveness:
//   xs   [32][68]     0..2175     ph1-2b
//   ex   [19][48]     2176..3087  ph2b-3
//   scl3 [2][32][48]  0..3071     written ph4b (xs/ex dead), read ph5
//   dts  [2][8][33]   3088..3615  ph3-4b (33-stride: ph4b j-varying reads)
//   els2 [2][32][8]   3616..4127  ph3-5
//   gco2 [2][32][8]   4128..4639  ph4b-5
//   CBl  [2][8][8]    4640..4767  ph4-4b
// ---------------------------------------------------------------------------
#define XS(r,k)       uni[(r)*68 + (k)]
#define EX(r,c)       uni[2176 + (r)*48 + (c)]
#define SCL3(cw,h,o)  uni[(((cw)*32+(h))*48) + (o)]
#define DTS(cw,i,h)   uni[3088 + ((cw)*8+(i))*33 + (h)]
#define ELS2(cw,h,i)  uni[3616 + (((cw)*32+(h))*8) + (i)]
#define GCO2(cw,h,j)  uni[4128 + (((cw)*32+(h))*8) + (j)]
#define CBL(cw,i,j)   uni[4640 + (cw)*64 + (i)*8 + (j)]

__global__ __launch_bounds__(256) void fused_kernel(
    const float* __restrict__ x,            // [NTOK][57]
    const unsigned short* __restrict__ Wbf, // [1024][64] bf16
    const float* __restrict__ WcT,          // [57][1072] fp32
    const float* __restrict__ bcomb,        // [1072]
    const float* __restrict__ conv_w,       // [528][4]
    const float* __restrict__ conv_b,       // [528]
    const float* __restrict__ dt_bias,      // [32]
    const float* __restrict__ A_log,        // [32]
    const float* __restrict__ Dvec,         // [32]
    unsigned* __restrict__ SGg,             // [B*NCH][32][128] packed lo=S' hi=G'
    float* __restrict__ cdec,               // [B*NCH][32]  = d0*d1
    float* __restrict__ pred)               // [B][32][512] atomic accum
{
    __shared__ __attribute__((aligned(16))) float uni[4768];   // 19072 B
    __shared__ __attribute__((aligned(16))) float BC[2][8][20]; // 1280 B

    const int blk = blockIdx.x;
    const int b = blk >> 8, cp = blk & 255;
    const int scBase = (b << 8) + cp;          // superchunk index
    const int tid = threadIdx.x;
    const long t0 = (long)b*SEQLEN + (long)cp*16;
    const bool first = (cp == 0);

    // ---- phase 1: stage 32 x rows (t0-16 .. t0+15), k padded ----
    #pragma unroll
    for (int it = 0; it < 8; ++it) {
        int idx = tid + it*256;
        int r = idx >> 6, k = idx & 63;
        float v = 0.f;
        if (k < INPUT_DIM && (r >= 16 || !first))
            v = x[(t0 - 16 + r)*INPUT_DIM + k];
        XS(r, k) = v;
    }
    __syncthreads();

    const int lane = tid & 63, wv = tid >> 6;
    const int quad = lane >> 4, mrow = lane & 15;

    // A fragments (regs; survive table overwrite of xs) — packed cvt
    bf16x8 aM[2], aH[2];
    #pragma unroll
    for (int hf = 0; hf < 2; ++hf) {
        const float* sm = &XS(16 + mrow, hf*32 + quad*8);
        const float* sh = &XS(mrow,      hf*32 + quad*8);
        unsigned* pm = (unsigned*)&aM[hf];
        unsigned* ph = (unsigned*)&aH[hf];
        #pragma unroll
        for (int j = 0; j < 4; ++j) {
            pm[j] = pack_bf2(sm[2*j], sm[2*j+1]);
            ph[j] = pack_bf2(sh[2*j], sh[2*j+1]);
        }
    }

    // ---- phase 2b: fp32 extras (48 cols x 19 rows, K=57) ----
    if (tid < 192) {
        const int col = tid % 48;
        const int grp = tid / 48;              // 0..3
        const int r0 = grp*5;
        const int nr = (grp == 3) ? 4 : 5;
        const float be = bcomb[1024 + col];
        float a[5];
        #pragma unroll
        for (int j = 0; j < 5; ++j) a[j] = be;
        for (int k = 0; k < INPUT_DIM; ++k) {
            const float w = WcT[(size_t)k*D_INPROJ + 1024 + col];
            #pragma unroll
            for (int j = 0; j < 5; ++j)
                if (j < nr) a[j] += w*XS(13 + r0 + j, k);
        }
        #pragma unroll
        for (int j = 0; j < 5; ++j) {
            if (j < nr) {
                int r = r0 + j;
                EX(r, col) = (first && r < 3) ? 0.f : a[j];
            }
        }
    }
    __syncthreads();   // ex visible; xs reads done (A-frags in regs)

    // ---- phase 3: B/C conv+silu (32 lanes) and dt chain (64 lanes) ----
    if (tid < 32) {
        const int cw = tid >> 4, q = tid & 15;
        const int ch = 512 + q;
        const float4 cw4 = *(const float4*)&conv_w[ch*4];
        const float cb = conv_b[ch];
        float s0 = EX(cw*8+0, q), s1 = EX(cw*8+1, q), s2 = EX(cw*8+2, q);
        #pragma unroll
        for (int i = 0; i < 8; ++i) {
            float s3 = EX(cw*8+i+3, q);
            float v = cb + s0*cw4.x + s1*cw4.y + s2*cw4.z + s3*cw4.w;
            v = fsilu(v);
            BC[cw][i][q] = v;                  // B at cols 0-7, C at 8-15
            s0 = s1; s1 = s2; s2 = s3;
        }
    } else if (tid >= 64 && tid < 128) {
        const int cw = (tid - 64) >> 5, h = (tid - 64) & 31;
        const float Ah = -__expf(A_log[h]);
        const float db = dt_bias[h];
        float ca = 0.f;
        #pragma unroll
        for (int i = 0; i < 8; ++i) {
            float raw = EX(cw*8 + i + 3, 16 + h) + db;
            float dt = (raw > 20.f) ? raw : log1pf(__expf(raw));
            DTS(cw, i, h) = dt;
            ca += dt * Ah;
            ELS2(cw, h, i) = __expf(ca);
        }
    }
    __syncthreads();

    // ---- phase 4: CB = C B^T per chunk; cdec' = d0*d1 ----
    if (tid < 128) {
        const int cw = tid >> 6, i = (tid >> 3) & 7, j = tid & 7;
        float s = 0.f;
        #pragma unroll
        for (int n = 0; n < 8; ++n) s += BC[cw][i][8+n]*BC[cw][j][n];
        CBL(cw, i, j) = s;
    } else if (tid < 160) {
        const int h = tid - 128;
        cdec[(size_t)scBase*32 + h] = ELS2(0, h, 7) * ELS2(1, h, 7);
    }
    __syncthreads();

    // ---- phase 4b: coefficient tables, h-major zero-padded (over xs/ex).
    // exp(cA_i - cA_j) computed as els_i / els_j (cAl table deleted). ----
    #pragma unroll
    for (int q = 0; q < 12; ++q) {             // 3072 = 2*32*48
        int idx = tid + q*256;
        int ofs = idx % 48;
        int hc  = idx / 48;
        int h2 = hc & 31, cw2 = hc >> 5;
        int i, j;
        if (ofs < 16) { i = ofs >> 2; j = ofs & 3; }
        else { int r2 = ofs - 16; i = 4 + (r2 >> 3); j = r2 & 7; }
        float v = 0.f;
        if (j <= i)
            v = CBL(cw2, i, j)
              * (ELS2(cw2, h2, i) / ELS2(cw2, h2, j)) * DTS(cw2, j, h2);
        SCL3(cw2, h2, ofs) = v;
    }
    #pragma unroll
    for (int q = 0; q < 2; ++q) {              // 512 = 2*32*8
        int idx = tid + q*256;
        int j = idx & 7; int hc = idx >> 3;
        int h2 = hc & 31, cw2 = hc >> 5;
        GCO2(cw2, h2, j) = (ELS2(cw2, h2, 7) / ELS2(cw2, h2, j)) * DTS(cw2, j, h2);
    }
    __syncthreads();

    // ---- phase 5: barrier-free tile loop. Lane owns z col `col` and x col
    // `col+512`, rows quad*4..quad*4+3. cw = quad>>1; joff = (quad&1)*4. ----
    const int cw   = quad >> 1;
    const int joff = (quad & 1) * 4;
    const int jpo  = joff ^ 4;                 // partner quad's row base
    const int srcConv = (lane + 48) & 63;      // lane - 16 (mod 64)
    const float zm = (quad & 1) ? 0.f : 1.f;   // rows 0-3 have no j>=4 terms

    #pragma unroll
    for (int t = 0; t < 8; ++t) {
        const int g   = wv + 4*t;              // 0..31 = head h
        const int h   = g;
        const int col = g*16 + mrow;           // z col; x col = col+512

        // z MFMA
        const unsigned short* wpz = &Wbf[(size_t)col*64];
        bf16x8 bz0 = *(const bf16x8*)&wpz[quad*8];
        bf16x8 bz1 = *(const bf16x8*)&wpz[32 + quad*8];
        const float bvz = bcomb[col];
        f32x4 accZ; accZ.x = bvz; accZ.y = bvz; accZ.z = bvz; accZ.w = bvz;
        accZ = __builtin_amdgcn_mfma_f32_16x16x32_bf16(aM[0], bz0, accZ, 0, 0, 0);
        accZ = __builtin_amdgcn_mfma_f32_16x16x32_bf16(aM[1], bz1, accZ, 0, 0, 0);

        // x MFMA: main + halo
        const unsigned short* wpx = &Wbf[(size_t)(col + 512)*64];
        bf16x8 bx0 = *(const bf16x8*)&wpx[quad*8];
        bf16x8 bx1 = *(const bf16x8*)&wpx[32 + quad*8];
        const float bvx = bcomb[col + 512];
        f32x4 accXM; accXM.x = bvx; accXM.y = bvx; accXM.z = bvx; accXM.w = bvx;
        accXM = __builtin_amdgcn_mfma_f32_16x16x32_bf16(aM[0], bx0, accXM, 0, 0, 0);
        accXM = __builtin_amdgcn_mfma_f32_16x16x32_bf16(aM[1], bx1, accXM, 0, 0, 0);
        f32x4 accXH; accXH.x = bvx; accXH.y = bvx; accXH.z = bvx; accXH.w = bvx;
        accXH = __builtin_amdgcn_mfma_f32_16x16x32_bf16(aH[0], bx0, accXH, 0, 0, 0);
        accXH = __builtin_amdgcn_mfma_f32_16x16x32_bf16(aH[1], bx1, accXH, 0, 0, 0);

        // conv halo: consumer quad q gets rows 4q-1,-2,-3 from lane-16
        float s1 = (quad == 3) ? accXH[3] : accXM[3];
        float s2 = (quad == 3) ? accXH[2] : accXM[2];
        float s3 = (quad == 3) ? accXH[1] : accXM[1];
        float r1 = __shfl(s1, srcConv, 64);
        float r2 = __shfl(s2, srcConv, 64);
        float r3 = __shfl(s3, srcConv, 64);
        if (first && quad == 0) { r1 = 0.f; r2 = 0.f; r3 = 0.f; }

        const float4 cw4 = *(const float4*)&conv_w[col*4];   // conv channel = col
        const float cb = conv_b[col];
        float vals[7] = {r3, r2, r1, accXM[0], accXM[1], accXM[2], accXM[3]};
        float xv[4], szv[4];
        #pragma unroll
        for (int r = 0; r < 4; ++r) {
            float v = cb + vals[r]*cw4.x + vals[r+1]*cw4.y + vals[r+2]*cw4.z + vals[r+3]*cw4.w;
            xv[r] = fsilu(v);
            szv[r] = fsilu(accZ[r]);
        }

        // attention partials: one b128 broadcast per row i (zero-padded tri)
        const float* sbase = &SCL3(cw, h, 0);
        float part[8];
        #pragma unroll
        for (int i = 0; i < 4; ++i) {
            f32x4 c4 = *(const f32x4*)&sbase[i*4];
            part[i] = zm*(c4[0]*xv[0] + c4[1]*xv[1] + c4[2]*xv[2] + c4[3]*xv[3]);
        }
        #pragma unroll
        for (int i = 4; i < 8; ++i) {
            f32x4 c4 = *(const f32x4*)&sbase[16 + (i-4)*8 + joff];
            part[i] = c4[0]*xv[0] + c4[1]*xv[1] + c4[2]*xv[2] + c4[3]*xv[3];
        }

        // combine with quad partner; pooled intra
        const float Dv = Dvec[h];
        float pa = 0.f;
        #pragma unroll
        for (int r = 0; r < 4; ++r) {
            float mine   = (quad & 1) ? part[4+r] : part[r];
            float theirs = (quad & 1) ? part[r]   : part[4+r];
            float other  = __shfl_xor(theirs, 16, 64);
            float y = Dv*xv[r] + mine + other;
            pa += y * szv[r];
        }
        pa += __shfl_xor(pa, 16, 64);          // quads 0/1: chunk0 pa; 2/3: chunk1
        float paO = __shfl_xor(pa, 32, 64);    // other chunk's pa

        // (S,g): n-split across the quad pair. Lane computes states
        // n = joff..joff+3 over ALL 8 rows of chunk cw; partner-row products
        // arrive via transient fp32 xor16 shfl INSIDE the loop (no arrays).
        f32x4 G4 = *(const f32x4*)&GCO2(cw, h, joff);
        f32x4 E4 = *(const f32x4*)&ELS2(cw, h, joff);
        float sn[4] = {0.f,0.f,0.f,0.f}, gg[4] = {0.f,0.f,0.f,0.f};
        #pragma unroll
        for (int r = 0; r < 4; ++r) {
            float uuO = G4[r]*xv[r];           // own row joff+r
            float wO  = szv[r]*E4[r];
            float uuP = __shfl_xor(uuO, 16, 64);  // partner row jpo+r
            float wP  = __shfl_xor(wO, 16, 64);
            const float4 BvO = *(const float4*)&BC[cw][joff+r][joff];
            const float4 CvO = *(const float4*)&BC[cw][joff+r][8+joff];
            const float4 BvP = *(const float4*)&BC[cw][jpo+r][joff];
            const float4 CvP = *(const float4*)&BC[cw][jpo+r][8+joff];
            sn[0] += uuO*BvO.x + uuP*BvP.x;
            sn[1] += uuO*BvO.y + uuP*BvP.y;
            sn[2] += uuO*BvO.z + uuP*BvP.z;
            sn[3] += uuO*BvO.w + uuP*BvP.w;
            gg[0] += wO*CvO.x + wP*CvP.x;
            gg[1] += wO*CvO.y + wP*CvP.y;
            gg[2] += wO*CvO.z + wP*CvP.z;
            gg[3] += wO*CvO.w + wP*CvP.w;
        }
        // cross-chunk compose in fp32 (quads 0/1 own chunk0; +32 = chunk1):
        //   S' = S0*d1 + S1;  G' = g0 + d0*g1;  local = sum_n S0*g1
        const float d0 = ELS2(0, h, 7), d1 = ELS2(1, h, 7);
        float local = 0.f;
        unsigned up[4] __attribute__((aligned(16)));
        #pragma unroll
        for (int n = 0; n < 4; ++n) {
            float So = __shfl_xor(sn[n], 32, 64);
            float go = __shfl_xor(gg[n], 32, 64);
            float Sp = sn[n]*d1 + So;
            float Gp = gg[n] + d0*go;
            local += sn[n]*go;
            up[n] = pack_bf2(Sp, Gp);
        }
        local += __shfl_xor(local, 16, 64);    // states 0-3 part + 4-7 part
        if (quad == 0)
            atomicAdd(&pred[((size_t)(b*32) + (cp >> 3))*512 + col], pa + paO + local);
        if (quad < 2) {
            unsigned* dst = &SGg[((size_t)scBase*32 + h)*128 + mrow*8 + joff];
            *(uint4*)&dst[0] = *(uint4*)&up[0];
        }
    }
}

// ---------------------------------------------------------------------------
// A2 pass 1: element-parallel segmented scan over superchunks.
// ---------------------------------------------------------------------------
__global__ __launch_bounds__(128) void scanseg_kernel(
    const unsigned* __restrict__ SGg,  // [B*NCH][32][128] packed
    const float* __restrict__ cdec,    // [B*NCH][32]
    float* __restrict__ Sloc,          // [8192][128]
    float* __restrict__ Gseg,
    float* __restrict__ Aseg,
    float* __restrict__ ploc)          // [8192][16]
{
    const int blk = blockIdx.x;             // (b*32+h)*NSEG + seg
    const int seg = blk & (NSEG-1);
    const int bh  = blk >> 4;
    const int b = bh >> 5, h = bh & 31;
    const int tid = threadIdx.x;
    const int c0 = seg*SEGC;

    float s = 0.f, P = 1.f, G = 0.f, pooled = 0.f;
    const unsigned* src = &SGg[((size_t)(b*NCH + c0)*32 + h)*128 + tid];
    const float* dsrc = &cdec[(b*NCH + c0)*32 + h];

    #pragma unroll 4
    for (int cc = 0; cc < SEGC; ++cc) {
        unsigned u = src[(size_t)cc*4096];
        float d = dsrc[cc*32];
        float Sv = __uint_as_float(u << 16);
        float gv = __uint_as_float(u & 0xffff0000u);
        pooled += s * gv;
        G += P * gv;
        P *= d;
        s = s*d + Sv;
    }
    Sloc[(size_t)blk*128 + tid] = s;
    Gseg[(size_t)blk*128 + tid] = G;
    if (tid == 0) Aseg[blk] = P;

    float t = pooled;
    t += __shfl_down(t, 4, 8);
    t += __shfl_down(t, 2, 8);
    t += __shfl_down(t, 1, 8);
    if ((tid & 7) == 0) ploc[(size_t)blk*16 + (tid >> 3)] = t;
}

// ---------------------------------------------------------------------------
// FINAL v2: scancomb merged in. Thread tid = h*16 + p computes the NSEG-
// segment combine for its 8 chains (n = p*8..p*8+7) of head h — exactly the
// partial_inter[b][tid] slot the old pipeline stored — then does the pooled
// reduction and classifier as before. One less launch; pIt buffer deleted.
// ---------------------------------------------------------------------------
__global__ __launch_bounds__(512) void final_kernel(
    const float* __restrict__ Sloc,    // [8192][128]
    const float* __restrict__ Gseg,
    const float* __restrict__ Aseg,
    const float* __restrict__ ploc,    // [8192][16]
    const float* __restrict__ pred,    // [B][32][512]
    const float* __restrict__ W_oc,    // [6][512]
    const float* __restrict__ b_cls,   // [6]
    float* __restrict__ out)           // [B][6]
{
    __shared__ double pooled[512];
    const int b = blockIdx.x, tid = threadIdx.x;
    const int h = tid >> 4, p = tid & 15;
    const int bh = b*32 + h;

    // scancomb role: 8 scan-chains over NSEG segments (float4-paired loads)
    float s0 = 0.f, s1 = 0.f, s2 = 0.f, s3 = 0.f;
    float s4 = 0.f, s5 = 0.f, s6 = 0.f, s7 = 0.f;
    double acc = 0.0;
    for (int seg = 0; seg < NSEG; ++seg) {
        size_t base = (size_t)(bh*NSEG + seg);
        float Av = Aseg[base];
        const float4 G0 = *(const float4*)&Gseg[base*128 + p*8];
        const float4 G1 = *(const float4*)&Gseg[base*128 + p*8 + 4];
        const float4 S0 = *(const float4*)&Sloc[base*128 + p*8];
        const float4 S1 = *(const float4*)&Sloc[base*128 + p*8 + 4];
        acc += (double)(s0*G0.x) + (double)(s1*G0.y)
             + (double)(s2*G0.z) + (double)(s3*G0.w)
             + (double)(s4*G1.x) + (double)(s5*G1.y)
             + (double)(s6*G1.z) + (double)(s7*G1.w);
        s0 = s0*Av + S0.x; s1 = s1*Av + S0.y;
        s2 = s2*Av + S0.z; s3 = s3*Av + S0.w;
        s4 = s4*Av + S1.x; s5 = s5*Av + S1.y;
        s6 = s6*Av + S1.z; s7 = s7*Av + S1.w;
    }
    for (int seg = 0; seg < NSEG; ++seg)
        acc += (double)ploc[(size_t)(bh*NSEG + seg)*16 + p];

    // pooled reduction + classifier (unchanged arithmetic)
    double ssum = 0.0;
    for (int g = 0; g < 32; ++g)
        ssum += (double)pred[((size_t)(b*32) + g)*512 + tid];
    ssum += acc;
    pooled[tid] = ssum * (1.0/(double)SEQLEN);
    __syncthreads();
    if (tid < OUT_SIZE*64) {
        const int o = tid >> 6, l = tid & 63;
        double a = 0.0;
        for (int m = l; m < 512; m += 64)
            a += pooled[m] * (double)W_oc[o*512 + m];
        #pragma unroll
        for (int off = 32; off > 0; off >>= 1)
            a += __shfl_down(a, off);
        if (l == 0) out[b*OUT_SIZE + o] = (float)(a + (double)b_cls[o]);
    }
}

// ---------------------------------------------------------------------------
extern "C" void kernel_launch(void* const* d_in, const int* in_sizes, int n_in,
                              void* d_out, int out_size, void* d_ws, size_t ws_size,
                              hipStream_t stream)
{
    const float* x        = (const float*)d_in[0];
    const float* W_in     = (const float*)d_in[1];
    const float* b_in     = (const float*)d_in[2];
    const float* W_inproj = (const float*)d_in[3];
    const float* conv_w   = (const float*)d_in[4];
    const float* conv_b   = (const float*)d_in[5];
    const float* dt_bias  = (const float*)d_in[6];
    const float* A_log    = (const float*)d_in[7];
    const float* Dvec     = (const float*)d_in[8];
    const float* W_out    = (const float*)d_in[9];
    const float* W_cls    = (const float*)d_in[10];
    const float* b_cls    = (const float*)d_in[11];
    float* out = (float*)d_out;

    char* ws = (char*)d_ws;
    size_t off = 0;
    auto alloc = [&](size_t bytes) -> void* {
        void* p = ws + off;
        off += (bytes + 255) & ~(size_t)255;
        return p;
    };
    unsigned* SGg = (unsigned*)alloc((size_t)BATCH*NCH*32*128*4);       // 67.1 MB
    float*  cdecb = (float*) alloc((size_t)BATCH*NCH*32*4);             // 0.5 MB
    float*  SlocB = (float*) alloc((size_t)BATCH*NHEADS*NSEG*128*4);    // 4.2 MB
    float*  GsegB = (float*) alloc((size_t)BATCH*NHEADS*NSEG*128*4);    // 4.2 MB
    float*  AsegB = (float*) alloc((size_t)BATCH*NHEADS*NSEG*4);
    float*  plocB = (float*) alloc((size_t)BATCH*NHEADS*NSEG*16*4);     // 0.5 MB
    float*  pred  = (float*) alloc((size_t)BATCH*32*512*4);             // 1.0 MB
    float*  WcT   = (float*) alloc((size_t)INPUT_DIM*D_INPROJ*4);
    float*  bcomb = (float*) alloc((size_t)D_INPROJ*4);
    unsigned short* Wbf = (unsigned short*)alloc((size_t)1024*64*2);    // 128 KB
    float*  Woc   = (float*) alloc((size_t)OUT_SIZE*D_INNER*4);
    if (off > ws_size) return;   // diagnostic: absmax-fail instead of fault

    precompute_kernel<<<D_INPROJ + D_INNER, 256, 0, stream>>>(W_in, b_in, W_inproj, W_out, W_cls,
                                                              WcT, bcomb, Wbf, Woc, pred);
    fused_kernel<<<BATCH*NC/2, 256, 0, stream>>>(x, Wbf, WcT, bcomb, conv_w, conv_b,
                                                 dt_bias, A_log, Dvec, SGg, cdecb, pred);
    scanseg_kernel<<<BATCH*NHEADS*NSEG, 128, 0, stream>>>(SGg, cdecb, SlocB, GsegB, AsegB, plocB);
    final_kernel<<<BATCH, 512, 0, stream>>>(SlocB, GsegB, AsegB, plocB, pred, Woc, b_cls, out);
}

// Round 12
// 268.950 us; speedup vs baseline: 1.0182x; 1.0182x over previous
//
#include <hip/hip_runtime.h>
#include <math.h>

#define BATCH 16
#define SEQLEN 4096
#define INPUT_DIM 57
#define D_MODEL 256
#define D_INNER 512
#define D_STATE 8
#define HEADDIM 16
#define NHEADS 32
#define CHUNK 8
#define NC (SEQLEN/CHUNK)          // 512
#define NCH (NC/2)                 // 256 superchunks (2 chunks composed)
#define CONV_DIM 528
#define D_INPROJ 1072
#define OUT_SIZE 6
#define NTOK (BATCH*SEQLEN)        // 65536
#define NSEG 16                    // segments per (b,h)
#define SEGC (NCH/NSEG)            // 16 superchunks per segment

__device__ __forceinline__ unsigned short f2bf(float f) {   // RNE bf16, finite
    unsigned v = __float_as_uint(f);
    return (unsigned short)((v + 0x7fffu + ((v >> 16) & 1u)) >> 16);
}
// HW packed RNE f32->bf16 pair: dst.lo = bf(lo), dst.hi = bf(hi). 1 VALU inst.
__device__ __forceinline__ unsigned pack_bf2(float lo, float hi) {
    unsigned r;
    asm("v_cvt_pk_bf16_f32 %0, %1, %2" : "=v"(r) : "v"(lo), "v"(hi));
    return r;
}
__device__ __forceinline__ float fsilu(float v) {
    return v * __builtin_amdgcn_rcpf(1.f + __expf(-v));
}

typedef __attribute__((ext_vector_type(8))) short bf16x8;
typedef __attribute__((ext_vector_type(4))) float f32x4;

// ---------------------------------------------------------------------------
// P0 v3: fold W_in into W_inproj etc.; also zeroes pred (fused atomically
// accumulates into it now).
// ---------------------------------------------------------------------------
__global__ __launch_bounds__(256) void precompute_kernel(
    const float* __restrict__ W_in,
    const float* __restrict__ b_in,
    const float* __restrict__ W_inproj,
    const float* __restrict__ W_out,
    const float* __restrict__ W_cls,
    float* __restrict__ WcT,    // [57][1072]
    float* __restrict__ b_comb, // [1072]
    unsigned short* __restrict__ Wbf, // [1024][64]
    float* __restrict__ W_oc,   // [6][512]
    float* __restrict__ pred)   // [B][32][512] zero-fill
{
    __shared__ double red[256];
    const int blk = blockIdx.x;
    const int tid = threadIdx.x;
    if (blk < D_INPROJ) {
        const int n = blk;
        const int t = tid & 63, ms = tid >> 6;      // ms = 0..3
        double a0 = 0.0, a1 = 0.0;
        const int m0 = ms*64;
        if (t < INPUT_DIM) {
            for (int m = m0; m < m0 + 64; m += 2) {
                a0 += (double)W_inproj[n*D_MODEL+m  ] * (double)W_in[(m  )*INPUT_DIM+t];
                a1 += (double)W_inproj[n*D_MODEL+m+1] * (double)W_in[(m+1)*INPUT_DIM+t];
            }
        } else if (t == INPUT_DIM) {
            for (int m = m0; m < m0 + 64; m += 2) {
                a0 += (double)W_inproj[n*D_MODEL+m  ] * (double)b_in[m  ];
                a1 += (double)W_inproj[n*D_MODEL+m+1] * (double)b_in[m+1];
            }
        }
        red[tid] = a0 + a1;
        __syncthreads();
        if (tid < 64) {
            double acc = (red[tid] + red[tid+64]) + (red[tid+128] + red[tid+192]);
            if (t < INPUT_DIM) {
                WcT[t*D_INPROJ + n] = (float)acc;
                if (n < 1024) Wbf[n*64 + t] = f2bf((float)acc);
            } else {
                if (t == INPUT_DIM) b_comb[n] = (float)acc;
                if (n < 1024) Wbf[n*64 + t] = 0;   // k pad 57..63
            }
        }
    } else {
        const int d = blk - D_INPROJ;               // 0..511
        // zero pred (262144 floats / 512 blocks / 256 threads = 2 each)
        const int zi = d*256 + tid;
        pred[zi] = 0.f;
        pred[zi + 131072] = 0.f;
        const int o = tid >> 5;          // 0..7 (6 active)
        const int lp = tid & 31;
        double a = 0.0;
        if (o < OUT_SIZE) {
            const int m0 = lp*8;
            #pragma unroll
            for (int mm = 0; mm < 8; ++mm) {
                int m = m0 + mm;
                a += (double)W_cls[o*D_MODEL+m] * (double)W_out[m*D_INNER+d];
            }
        }
        #pragma unroll
        for (int off = 16; off > 0; off >>= 1)
            a += __shfl_down(a, off, 32);
        if (o < OUT_SIZE && lp == 0)
            W_oc[o*D_INNER + d] = (float)a;
    }
}

// ---------------------------------------------------------------------------
// FUSED v3.1 (best known: ~181 us, VGPR 44): register-disciplined n-split.
// Each quad computes states n = joff..joff+3 over ALL 8 rows of its chunk;
// partner-row products via transient fp32 xor16 shfl inside the r-loop.
// quad0 writes SGg words 0-3, quad1 words 4-7.
//
// LDS arena 'uni' (float word offsets), regions by liveness:
//   xs   [32][68]     0..2175     ph1-2b
//   ex   [19][48]     2176..3087  ph2b-3
//   scl3 [2][32][48]  0..3071     written ph4b (xs/ex dead), read ph5
//   dts  [2][8][33]   3088..3615  ph3-4b (33-stride: ph4b j-varying reads)
//   els2 [2][32][8]   3616..4127  ph3-5
//   gco2 [2][32][8]   4128..4639  ph4b-5
//   CBl  [2][8][8]    4640..4767  ph4-4b
// ---------------------------------------------------------------------------
#define XS(r,k)       uni[(r)*68 + (k)]
#define EX(r,c)       uni[2176 + (r)*48 + (c)]
#define SCL3(cw,h,o)  uni[(((cw)*32+(h))*48) + (o)]
#define DTS(cw,i,h)   uni[3088 + ((cw)*8+(i))*33 + (h)]
#define ELS2(cw,h,i)  uni[3616 + (((cw)*32+(h))*8) + (i)]
#define GCO2(cw,h,j)  uni[4128 + (((cw)*32+(h))*8) + (j)]
#define CBL(cw,i,j)   uni[4640 + (cw)*64 + (i)*8 + (j)]

__global__ __launch_bounds__(256) void fused_kernel(
    const float* __restrict__ x,            // [NTOK][57]
    const unsigned short* __restrict__ Wbf, // [1024][64] bf16
    const float* __restrict__ WcT,          // [57][1072] fp32
    const float* __restrict__ bcomb,        // [1072]
    const float* __restrict__ conv_w,       // [528][4]
    const float* __restrict__ conv_b,       // [528]
    const float* __restrict__ dt_bias,      // [32]
    const float* __restrict__ A_log,        // [32]
    const float* __restrict__ Dvec,         // [32]
    unsigned* __restrict__ SGg,             // [B*NCH][32][128] packed lo=S' hi=G'
    float* __restrict__ cdec,               // [B*NCH][32]  = d0*d1
    float* __restrict__ pred)               // [B][32][512] atomic accum
{
    __shared__ __attribute__((aligned(16))) float uni[4768];   // 19072 B
    __shared__ __attribute__((aligned(16))) float BC[2][8][20]; // 1280 B

    const int blk = blockIdx.x;
    const int b = blk >> 8, cp = blk & 255;
    const int scBase = (b << 8) + cp;          // superchunk index
    const int tid = threadIdx.x;
    const long t0 = (long)b*SEQLEN + (long)cp*16;
    const bool first = (cp == 0);

    // ---- phase 1: stage 32 x rows (t0-16 .. t0+15), k padded ----
    #pragma unroll
    for (int it = 0; it < 8; ++it) {
        int idx = tid + it*256;
        int r = idx >> 6, k = idx & 63;
        float v = 0.f;
        if (k < INPUT_DIM && (r >= 16 || !first))
            v = x[(t0 - 16 + r)*INPUT_DIM + k];
        XS(r, k) = v;
    }
    __syncthreads();

    const int lane = tid & 63, wv = tid >> 6;
    const int quad = lane >> 4, mrow = lane & 15;

    // A fragments (regs; survive table overwrite of xs) — packed cvt
    bf16x8 aM[2], aH[2];
    #pragma unroll
    for (int hf = 0; hf < 2; ++hf) {
        const float* sm = &XS(16 + mrow, hf*32 + quad*8);
        const float* sh = &XS(mrow,      hf*32 + quad*8);
        unsigned* pm = (unsigned*)&aM[hf];
        unsigned* ph = (unsigned*)&aH[hf];
        #pragma unroll
        for (int j = 0; j < 4; ++j) {
            pm[j] = pack_bf2(sm[2*j], sm[2*j+1]);
            ph[j] = pack_bf2(sh[2*j], sh[2*j+1]);
        }
    }

    // ---- phase 2b: fp32 extras (48 cols x 19 rows, K=57) ----
    if (tid < 192) {
        const int col = tid % 48;
        const int grp = tid / 48;              // 0..3
        const int r0 = grp*5;
        const int nr = (grp == 3) ? 4 : 5;
        const float be = bcomb[1024 + col];
        float a[5];
        #pragma unroll
        for (int j = 0; j < 5; ++j) a[j] = be;
        for (int k = 0; k < INPUT_DIM; ++k) {
            const float w = WcT[(size_t)k*D_INPROJ + 1024 + col];
            #pragma unroll
            for (int j = 0; j < 5; ++j)
                if (j < nr) a[j] += w*XS(13 + r0 + j, k);
        }
        #pragma unroll
        for (int j = 0; j < 5; ++j) {
            if (j < nr) {
                int r = r0 + j;
                EX(r, col) = (first && r < 3) ? 0.f : a[j];
            }
        }
    }
    __syncthreads();   // ex visible; xs reads done (A-frags in regs)

    // ---- phase 3: B/C conv+silu (32 lanes) and dt chain (64 lanes) ----
    if (tid < 32) {
        const int cw = tid >> 4, q = tid & 15;
        const int ch = 512 + q;
        const float4 cw4 = *(const float4*)&conv_w[ch*4];
        const float cb = conv_b[ch];
        float s0 = EX(cw*8+0, q), s1 = EX(cw*8+1, q), s2 = EX(cw*8+2, q);
        #pragma unroll
        for (int i = 0; i < 8; ++i) {
            float s3 = EX(cw*8+i+3, q);
            float v = cb + s0*cw4.x + s1*cw4.y + s2*cw4.z + s3*cw4.w;
            v = fsilu(v);
            BC[cw][i][q] = v;                  // B at cols 0-7, C at 8-15
            s0 = s1; s1 = s2; s2 = s3;
        }
    } else if (tid >= 64 && tid < 128) {
        const int cw = (tid - 64) >> 5, h = (tid - 64) & 31;
        const float Ah = -__expf(A_log[h]);
        const float db = dt_bias[h];
        float ca = 0.f;
        #pragma unroll
        for (int i = 0; i < 8; ++i) {
            float raw = EX(cw*8 + i + 3, 16 + h) + db;
            float dt = (raw > 20.f) ? raw : log1pf(__expf(raw));
            DTS(cw, i, h) = dt;
            ca += dt * Ah;
            ELS2(cw, h, i) = __expf(ca);
        }
    }
    __syncthreads();

    // ---- phase 4: CB = C B^T per chunk; cdec' = d0*d1 ----
    if (tid < 128) {
        const int cw = tid >> 6, i = (tid >> 3) & 7, j = tid & 7;
        float s = 0.f;
        #pragma unroll
        for (int n = 0; n < 8; ++n) s += BC[cw][i][8+n]*BC[cw][j][n];
        CBL(cw, i, j) = s;
    } else if (tid < 160) {
        const int h = tid - 128;
        cdec[(size_t)scBase*32 + h] = ELS2(0, h, 7) * ELS2(1, h, 7);
    }
    __syncthreads();

    // ---- phase 4b: coefficient tables, h-major zero-padded (over xs/ex).
    // exp(cA_i - cA_j) computed as els_i / els_j (cAl table deleted). ----
    #pragma unroll
    for (int q = 0; q < 12; ++q) {             // 3072 = 2*32*48
        int idx = tid + q*256;
        int ofs = idx % 48;
        int hc  = idx / 48;
        int h2 = hc & 31, cw2 = hc >> 5;
        int i, j;
        if (ofs < 16) { i = ofs >> 2; j = ofs & 3; }
        else { int r2 = ofs - 16; i = 4 + (r2 >> 3); j = r2 & 7; }
        float v = 0.f;
        if (j <= i)
            v = CBL(cw2, i, j)
              * (ELS2(cw2, h2, i) / ELS2(cw2, h2, j)) * DTS(cw2, j, h2);
        SCL3(cw2, h2, ofs) = v;
    }
    #pragma unroll
    for (int q = 0; q < 2; ++q) {              // 512 = 2*32*8
        int idx = tid + q*256;
        int j = idx & 7; int hc = idx >> 3;
        int h2 = hc & 31, cw2 = hc >> 5;
        GCO2(cw2, h2, j) = (ELS2(cw2, h2, 7) / ELS2(cw2, h2, j)) * DTS(cw2, j, h2);
    }
    __syncthreads();

    // ---- phase 5: barrier-free tile loop. Lane owns z col `col` and x col
    // `col+512`, rows quad*4..quad*4+3. cw = quad>>1; joff = (quad&1)*4. ----
    const int cw   = quad >> 1;
    const int joff = (quad & 1) * 4;
    const int jpo  = joff ^ 4;                 // partner quad's row base
    const int srcConv = (lane + 48) & 63;      // lane - 16 (mod 64)
    const float zm = (quad & 1) ? 0.f : 1.f;   // rows 0-3 have no j>=4 terms

    #pragma unroll
    for (int t = 0; t < 8; ++t) {
        const int g   = wv + 4*t;              // 0..31 = head h
        const int h   = g;
        const int col = g*16 + mrow;           // z col; x col = col+512

        // z MFMA
        const unsigned short* wpz = &Wbf[(size_t)col*64];
        bf16x8 bz0 = *(const bf16x8*)&wpz[quad*8];
        bf16x8 bz1 = *(const bf16x8*)&wpz[32 + quad*8];
        const float bvz = bcomb[col];
        f32x4 accZ; accZ.x = bvz; accZ.y = bvz; accZ.z = bvz; accZ.w = bvz;
        accZ = __builtin_amdgcn_mfma_f32_16x16x32_bf16(aM[0], bz0, accZ, 0, 0, 0);
        accZ = __builtin_amdgcn_mfma_f32_16x16x32_bf16(aM[1], bz1, accZ, 0, 0, 0);

        // x MFMA: main + halo
        const unsigned short* wpx = &Wbf[(size_t)(col + 512)*64];
        bf16x8 bx0 = *(const bf16x8*)&wpx[quad*8];
        bf16x8 bx1 = *(const bf16x8*)&wpx[32 + quad*8];
        const float bvx = bcomb[col + 512];
        f32x4 accXM; accXM.x = bvx; accXM.y = bvx; accXM.z = bvx; accXM.w = bvx;
        accXM = __builtin_amdgcn_mfma_f32_16x16x32_bf16(aM[0], bx0, accXM, 0, 0, 0);
        accXM = __builtin_amdgcn_mfma_f32_16x16x32_bf16(aM[1], bx1, accXM, 0, 0, 0);
        f32x4 accXH; accXH.x = bvx; accXH.y = bvx; accXH.z = bvx; accXH.w = bvx;
        accXH = __builtin_amdgcn_mfma_f32_16x16x32_bf16(aH[0], bx0, accXH, 0, 0, 0);
        accXH = __builtin_amdgcn_mfma_f32_16x16x32_bf16(aH[1], bx1, accXH, 0, 0, 0);

        // conv halo: consumer quad q gets rows 4q-1,-2,-3 from lane-16
        float s1 = (quad == 3) ? accXH[3] : accXM[3];
        float s2 = (quad == 3) ? accXH[2] : accXM[2];
        float s3 = (quad == 3) ? accXH[1] : accXM[1];
        float r1 = __shfl(s1, srcConv, 64);
        float r2 = __shfl(s2, srcConv, 64);
        float r3 = __shfl(s3, srcConv, 64);
        if (first && quad == 0) { r1 = 0.f; r2 = 0.f; r3 = 0.f; }

        const float4 cw4 = *(const float4*)&conv_w[col*4];   // conv channel = col
        const float cb = conv_b[col];
        float vals[7] = {r3, r2, r1, accXM[0], accXM[1], accXM[2], accXM[3]};
        float xv[4], szv[4];
        #pragma unroll
        for (int r = 0; r < 4; ++r) {
            float v = cb + vals[r]*cw4.x + vals[r+1]*cw4.y + vals[r+2]*cw4.z + vals[r+3]*cw4.w;
            xv[r] = fsilu(v);
            szv[r] = fsilu(accZ[r]);
        }

        // attention partials: one b128 broadcast per row i (zero-padded tri)
        const float* sbase = &SCL3(cw, h, 0);
        float part[8];
        #pragma unroll
        for (int i = 0; i < 4; ++i) {
            f32x4 c4 = *(const f32x4*)&sbase[i*4];
            part[i] = zm*(c4[0]*xv[0] + c4[1]*xv[1] + c4[2]*xv[2] + c4[3]*xv[3]);
        }
        #pragma unroll
        for (int i = 4; i < 8; ++i) {
            f32x4 c4 = *(const f32x4*)&sbase[16 + (i-4)*8 + joff];
            part[i] = c4[0]*xv[0] + c4[1]*xv[1] + c4[2]*xv[2] + c4[3]*xv[3];
        }

        // combine with quad partner; pooled intra
        const float Dv = Dvec[h];
        float pa = 0.f;
        #pragma unroll
        for (int r = 0; r < 4; ++r) {
            float mine   = (quad & 1) ? part[4+r] : part[r];
            float theirs = (quad & 1) ? part[r]   : part[4+r];
            float other  = __shfl_xor(theirs, 16, 64);
            float y = Dv*xv[r] + mine + other;
            pa += y * szv[r];
        }
        pa += __shfl_xor(pa, 16, 64);          // quads 0/1: chunk0 pa; 2/3: chunk1
        float paO = __shfl_xor(pa, 32, 64);    // other chunk's pa

        // (S,g): n-split across the quad pair. Lane computes states
        // n = joff..joff+3 over ALL 8 rows of chunk cw; partner-row products
        // arrive via transient fp32 xor16 shfl INSIDE the loop (no arrays).
        f32x4 G4 = *(const f32x4*)&GCO2(cw, h, joff);
        f32x4 E4 = *(const f32x4*)&ELS2(cw, h, joff);
        float sn[4] = {0.f,0.f,0.f,0.f}, gg[4] = {0.f,0.f,0.f,0.f};
        #pragma unroll
        for (int r = 0; r < 4; ++r) {
            float uuO = G4[r]*xv[r];           // own row joff+r
            float wO  = szv[r]*E4[r];
            float uuP = __shfl_xor(uuO, 16, 64);  // partner row jpo+r
            float wP  = __shfl_xor(wO, 16, 64);
            const float4 BvO = *(const float4*)&BC[cw][joff+r][joff];
            const float4 CvO = *(const float4*)&BC[cw][joff+r][8+joff];
            const float4 BvP = *(const float4*)&BC[cw][jpo+r][joff];
            const float4 CvP = *(const float4*)&BC[cw][jpo+r][8+joff];
            sn[0] += uuO*BvO.x + uuP*BvP.x;
            sn[1] += uuO*BvO.y + uuP*BvP.y;
            sn[2] += uuO*BvO.z + uuP*BvP.z;
            sn[3] += uuO*BvO.w + uuP*BvP.w;
            gg[0] += wO*CvO.x + wP*CvP.x;
            gg[1] += wO*CvO.y + wP*CvP.y;
            gg[2] += wO*CvO.z + wP*CvP.z;
            gg[3] += wO*CvO.w + wP*CvP.w;
        }
        // cross-chunk compose in fp32 (quads 0/1 own chunk0; +32 = chunk1):
        //   S' = S0*d1 + S1;  G' = g0 + d0*g1;  local = sum_n S0*g1
        const float d0 = ELS2(0, h, 7), d1 = ELS2(1, h, 7);
        float local = 0.f;
        unsigned up[4] __attribute__((aligned(16)));
        #pragma unroll
        for (int n = 0; n < 4; ++n) {
            float So = __shfl_xor(sn[n], 32, 64);
            float go = __shfl_xor(gg[n], 32, 64);
            float Sp = sn[n]*d1 + So;
            float Gp = gg[n] + d0*go;
            local += sn[n]*go;
            up[n] = pack_bf2(Sp, Gp);
        }
        local += __shfl_xor(local, 16, 64);    // states 0-3 part + 4-7 part
        if (quad == 0)
            atomicAdd(&pred[((size_t)(b*32) + (cp >> 3))*512 + col], pa + paO + local);
        if (quad < 2) {
            unsigned* dst = &SGg[((size_t)scBase*32 + h)*128 + mrow*8 + joff];
            *(uint4*)&dst[0] = *(uint4*)&up[0];
        }
    }
}

// ---------------------------------------------------------------------------
// A2 pass 1: element-parallel segmented scan over superchunks.
// ---------------------------------------------------------------------------
__global__ __launch_bounds__(128) void scanseg_kernel(
    const unsigned* __restrict__ SGg,  // [B*NCH][32][128] packed
    const float* __restrict__ cdec,    // [B*NCH][32]
    float* __restrict__ Sloc,          // [8192][128]
    float* __restrict__ Gseg,
    float* __restrict__ Aseg,
    float* __restrict__ ploc)          // [8192][16]
{
    const int blk = blockIdx.x;             // (b*32+h)*NSEG + seg
    const int seg = blk & (NSEG-1);
    const int bh  = blk >> 4;
    const int b = bh >> 5, h = bh & 31;
    const int tid = threadIdx.x;
    const int c0 = seg*SEGC;

    float s = 0.f, P = 1.f, G = 0.f, pooled = 0.f;
    const unsigned* src = &SGg[((size_t)(b*NCH + c0)*32 + h)*128 + tid];
    const float* dsrc = &cdec[(b*NCH + c0)*32 + h];

    #pragma unroll 4
    for (int cc = 0; cc < SEGC; ++cc) {
        unsigned u = src[(size_t)cc*4096];
        float d = dsrc[cc*32];
        float Sv = __uint_as_float(u << 16);
        float gv = __uint_as_float(u & 0xffff0000u);
        pooled += s * gv;
        G += P * gv;
        P *= d;
        s = s*d + Sv;
    }
    Sloc[(size_t)blk*128 + tid] = s;
    Gseg[(size_t)blk*128 + tid] = G;
    if (tid == 0) Aseg[blk] = P;

    float t = pooled;
    t += __shfl_down(t, 4, 8);
    t += __shfl_down(t, 2, 8);
    t += __shfl_down(t, 1, 8);
    if ((tid & 7) == 0) ploc[(size_t)blk*16 + (tid >> 3)] = t;
}

// ---------------------------------------------------------------------------
// A2 pass 2: combine NSEG segments per (b,h). Device-parallel (512 blocks) —
// R11 lesson: folding this into final's 16 blocks serialized the 8.4 MB
// Sloc/Gseg read onto 16 CUs and cost more than the saved launch gap.
// ---------------------------------------------------------------------------
__global__ __launch_bounds__(128) void scancomb_kernel(
    const float* __restrict__ Sloc,
    const float* __restrict__ Gseg,
    const float* __restrict__ Aseg,
    const float* __restrict__ ploc,
    double* __restrict__ partial_inter) // [B][512]
{
    __shared__ double red[128];
    const int bh = blockIdx.x;              // b*32 + h
    const int tid = threadIdx.x;
    float s = 0.f;
    double acc = 0.0;
    for (int seg = 0; seg < NSEG; ++seg) {
        size_t base = (size_t)(bh*NSEG + seg);
        float Gv = Gseg[base*128 + tid];
        float Av = Aseg[base];
        float Sv = Sloc[base*128 + tid];
        acc += (double)(s * Gv);
        s = s*Av + Sv;
    }
    red[tid] = acc;
    __syncthreads();
    if (tid < 16) {
        double t = 0.0;
        #pragma unroll
        for (int n = 0; n < 8; ++n) t += red[tid*8 + n];
        for (int seg = 0; seg < NSEG; ++seg)
            t += (double)ploc[(size_t)(bh*NSEG + seg)*16 + tid];
        partial_inter[(size_t)bh*16 + tid] = t;
    }
}

// ---------------------------------------------------------------------------
__global__ __launch_bounds__(512) void final_kernel(
    const float* __restrict__ pred,           // [B][32][512]
    const double* __restrict__ partial_inter, // [B][512]
    const float* __restrict__ W_oc,           // [6][512]
    const float* __restrict__ b_cls,          // [6]
    float* __restrict__ out)                  // [B][6]
{
    __shared__ double pooled[512];
    const int b = blockIdx.x, tid = threadIdx.x;
    double ssum = 0.0;
    for (int g = 0; g < 32; ++g)
        ssum += (double)pred[((size_t)(b*32) + g)*512 + tid];
    ssum += partial_inter[(size_t)b*512 + tid];
    pooled[tid] = ssum * (1.0/(double)SEQLEN);
    __syncthreads();
    if (tid < OUT_SIZE*64) {
        const int o = tid >> 6, l = tid & 63;
        double acc = 0.0;
        for (int m = l; m < 512; m += 64)
            acc += pooled[m] * (double)W_oc[o*512 + m];
        #pragma unroll
        for (int off = 32; off > 0; off >>= 1)
            acc += __shfl_down(acc, off);
        if (l == 0) out[b*OUT_SIZE + o] = (float)(acc + (double)b_cls[o]);
    }
}

// ---------------------------------------------------------------------------
extern "C" void kernel_launch(void* const* d_in, const int* in_sizes, int n_in,
                              void* d_out, int out_size, void* d_ws, size_t ws_size,
                              hipStream_t stream)
{
    const float* x        = (const float*)d_in[0];
    const float* W_in     = (const float*)d_in[1];
    const float* b_in     = (const float*)d_in[2];
    const float* W_inproj = (const float*)d_in[3];
    const float* conv_w   = (const float*)d_in[4];
    const float* conv_b   = (const float*)d_in[5];
    const float* dt_bias  = (const float*)d_in[6];
    const float* A_log    = (const float*)d_in[7];
    const float* Dvec     = (const float*)d_in[8];
    const float* W_out    = (const float*)d_in[9];
    const float* W_cls    = (const float*)d_in[10];
    const float* b_cls    = (const float*)d_in[11];
    float* out = (float*)d_out;

    char* ws = (char*)d_ws;
    size_t off = 0;
    auto alloc = [&](size_t bytes) -> void* {
        void* p = ws + off;
        off += (bytes + 255) & ~(size_t)255;
        return p;
    };
    unsigned* SGg = (unsigned*)alloc((size_t)BATCH*NCH*32*128*4);       // 67.1 MB
    float*  cdecb = (float*) alloc((size_t)BATCH*NCH*32*4);             // 0.5 MB
    float*  SlocB = (float*) alloc((size_t)BATCH*NHEADS*NSEG*128*4);    // 4.2 MB
    float*  GsegB = (float*) alloc((size_t)BATCH*NHEADS*NSEG*128*4);    // 4.2 MB
    float*  AsegB = (float*) alloc((size_t)BATCH*NHEADS*NSEG*4);
    float*  plocB = (float*) alloc((size_t)BATCH*NHEADS*NSEG*16*4);     // 0.5 MB
    float*  pred  = (float*) alloc((size_t)BATCH*32*512*4);             // 1.0 MB
    double* pIt   = (double*)alloc((size_t)BATCH*512*8);                // 64 KB
    float*  WcT   = (float*) alloc((size_t)INPUT_DIM*D_INPROJ*4);
    float*  bcomb = (float*) alloc((size_t)D_INPROJ*4);
    unsigned short* Wbf = (unsigned short*)alloc((size_t)1024*64*2);    // 128 KB
    float*  Woc   = (float*) alloc((size_t)OUT_SIZE*D_INNER*4);
    if (off > ws_size) return;   // diagnostic: absmax-fail instead of fault

    precompute_kernel<<<D_INPROJ + D_INNER, 256, 0, stream>>>(W_in, b_in, W_inproj, W_out, W_cls,
                                                              WcT, bcomb, Wbf, Woc, pred);
    fused_kernel<<<BATCH*NC/2, 256, 0, stream>>>(x, Wbf, WcT, bcomb, conv_w, conv_b,
                                                 dt_bias, A_log, Dvec, SGg, cdecb, pred);
    scanseg_kernel<<<BATCH*NHEADS*NSEG, 128, 0, stream>>>(SGg, cdecb, SlocB, GsegB, AsegB, plocB);
    scancomb_kernel<<<BATCH*NHEADS, 128, 0, stream>>>(SlocB, GsegB, AsegB, plocB, pIt);
    final_kernel<<<BATCH, 512, 0, stream>>>(pred, pIt, Woc, b_cls, out);
}